// Round 2
// baseline (38.530 us; speedup 1.0000x reference)
//
#include <hip/hip_runtime.h>

// OneDimEquivalent: sequential nonlinear scan, parallelized via contraction
// (warm-up windows) + LDS lookup table for the 64-node Gauss-Legendre integral.
//
// Reference step (fp32):
//   s     = 1.44*k^2 + 0.64*u^2          (delta^2)
//   gi    = quadrature(s)                (smooth 1-D function -> LDS table)
//   k_new = 0.8*k + gi*(0.18*k + 0.1*v)  (contraction <= 0.872)
//   v_new = 0.8*v + 0.2*u                (contraction 0.8)
//   z     = 0.7*gi*k_new
//
// Wall time = (W + CHUNK) steps x per-step chain latency (ds_read-dominated).
// This round: W 128->64 (0.872^64 ~ 1.6e-4 residual, ~1e-5 in z), float2
// table (single ds_read_b64), one post-load FMA on the critical path.

#define N_TAB   4096          // table entries over s = delta^2 in [0, 32)
#define W_STEPS 64            // warm-up steps
#define CHUNK   4             // z outputs per thread
#define THREADS 256

// ---------------- Gauss-Legendre order-64 nodes (per-block, fp64 Newton) ----
__device__ __forceinline__ void gl_nodes_block(double* zs, double* wc) {
  __shared__ double aj[65], bj[65];
  const int tid = threadIdx.x;
  if (tid >= 2 && tid <= 64) {
    double dj = (double)tid;
    aj[tid] = (2.0 * dj - 1.0) / dj;
    bj[tid] = (dj - 1.0) / dj;
  }
  __syncthreads();
  if (tid < 64) {
    double x = cos(3.14159265358979323846 * ((double)tid + 0.75) / 64.5);
    double dp = 1.0;
    for (int it = 0; it < 4; ++it) {
      double p0 = 1.0, p1 = x;
      for (int j = 2; j <= 64; ++j) {
        // p2 = ((2j-1)x p1 - (j-1) p0)/j ; one dependent fma per j
        double p2 = fma(aj[j] * x, p1, -(bj[j] * p0));
        p0 = p1; p1 = p2;
      }
      dp = 64.0 * (x * p1 - p0) / (x * x - 1.0);
      x -= p1 / dp;
    }
    double w = 2.0 / ((1.0 - x * x) * dp * dp);
    // Match reference: nodes/weights scaled by A=5, cast to fp32.
    float zn = (float)(5.0 * x);
    float wn = (float)(5.0 * w);
    zs[tid] = (double)zn;
    // fold weight * exp(-z^2/2) / (2*pi)
    wc[tid] = (double)wn * exp(-0.5 * (double)zn * (double)zn)
              * 0.15915494309189535;
  }
  __syncthreads();
}

// gi at s = idx/128; 64-node sum, sech^2 in fp32, fp64 accumulation.
__device__ __forceinline__ float table_entry(int idx, const double* zs,
                                             const double* wc) {
  double d = sqrt((double)idx * (1.0 / 128.0));
  double acc = 0.0;
  for (int j = 0; j < 64; ++j) {
    float x2 = (float)(2.0 * d * zs[j]);     // 2*delta*z_j
    float e  = __expf(-fabsf(x2));
    float t  = 1.0f + e;
    acc += wc[j] * (double)(4.0f * e / (t * t));   // sech^2
  }
  return (float)acc;
}

__global__ void build_table_kernel(float* __restrict__ tabg) {
  __shared__ double zs[64], wc[64];
  gl_nodes_block(zs, wc);
  for (int idx = blockIdx.x * blockDim.x + threadIdx.x; idx <= N_TAB;
       idx += gridDim.x * blockDim.x)
    tabg[idx] = table_entry(idx, zs, wc);
}

// ---------------- main scan --------------------------------------------------
// Critical chain per step: mul,fma -> min -> cvt -> lshl -> ds_read_b64 -> sub,
// fma (lerp) -> fma (k_new). Everything else (u^2 term, th, v, z) is off-chain.
__device__ __forceinline__ float step(float& k, float& v, float uu,
                                      const float2* tab) {
  float cu = 81.92f * uu * uu;                       // off-chain (u known early)
  float x  = fminf(fmaf(184.32f * k, k, cu), 4095.99f);  // 128 * delta^2
  int   i  = (int)x;
  float f  = x - truncf(x);                          // parallel to cvt/addr
  float2 g = tab[i];                                 // single ds_read_b64
  float gi = fmaf(f, g.y - g.x, g.x);
  float th = fmaf(0.18f, k, 0.1f * v);               // parallel to lookup
  float kn = fmaf(gi, th, 0.8f * k);                 // one fma after load
  v = fmaf(0.2f, uu, 0.8f * v);
  k = kn;
  return 0.7f * gi * kn;
}

template <bool BUILD>
__global__ __launch_bounds__(THREADS, 2) void scan_kernel(
    const float* __restrict__ u, const float* __restrict__ tabg,
    float* __restrict__ out) {
  __shared__ float2 tab[N_TAB];          // tab[i] = (g[i], g[i+1]), 32 KiB
  if constexpr (BUILD) {
    __shared__ double zs[64], wc[64];
    gl_nodes_block(zs, wc);
    for (int i = threadIdx.x; i < N_TAB; i += THREADS)
      tab[i] = make_float2(table_entry(i, zs, wc), table_entry(i + 1, zs, wc));
  } else {
    for (int i = threadIdx.x; i < N_TAB; i += THREADS)
      tab[i] = make_float2(tabg[i], tabg[i + 1]);
  }
  __syncthreads();

  const int t      = blockIdx.x * THREADS + threadIdx.x;  // chunk id
  const int g4     = t * CHUNK;                           // first z index
  const int wsteps = min(W_STEPS, g4);                    // multiple of 4
  const int ngrp   = wsteps >> 2;
  const float4* __restrict__ up = (const float4*)(u + (g4 - wsteps));

  float k = 0.0f, v = 0.0f;
  float4 cur = up[0];
  for (int g = 0; g < ngrp; ++g) {        // warm-up: converge to true state
    float4 nxt = up[g + 1];               // prefetch next 4 inputs
    step(k, v, cur.x, tab);
    step(k, v, cur.y, tab);
    step(k, v, cur.z, tab);
    step(k, v, cur.w, tab);
    cur = nxt;
  }
  float z0 = step(k, v, cur.x, tab);      // emit chunk outputs
  float z1 = step(k, v, cur.y, tab);
  float z2 = step(k, v, cur.z, tab);
  float z3 = step(k, v, cur.w, tab);
  out[g4 + 1] = z0;
  out[g4 + 2] = z1;
  out[g4 + 3] = z2;
  out[g4 + 4] = z3;
  if (t == 0) out[0] = 0.0f;              // z_hist[0] = 0
}

extern "C" void kernel_launch(void* const* d_in, const int* in_sizes, int n_in,
                              void* d_out, int out_size, void* d_ws,
                              size_t ws_size, hipStream_t stream) {
  const float* u = (const float*)d_in[0];
  float* out = (float*)d_out;
  const int T = in_sizes[0];                       // 524288
  const int nblock = T / (CHUNK * THREADS);        // 512

  if (d_ws && ws_size >= (N_TAB + 1) * sizeof(float)) {
    float* tabg = (float*)d_ws;
    build_table_kernel<<<32, 128, 0, stream>>>(tabg);
    scan_kernel<false><<<nblock, THREADS, 0, stream>>>(u, tabg, out);
  } else {
    scan_kernel<true><<<nblock, THREADS, 0, stream>>>(u, nullptr, out);
  }
}

// Round 3
// 23.329 us; speedup vs baseline: 1.6516x; 1.6516x over previous
//
#include <hip/hip_runtime.h>

// OneDimEquivalent: T=524288-step contracting scan, parallelized by warm-up
// windows (contraction factor <= 0.872 per step -> 64 warm-up steps leave
// ~1.6e-4 state residual, ~4e-5 in z). gi(s), s = delta^2, is evaluated by
// 4-point cubic Lagrange on a 512-cell LDS table (h = 1/16, interp err
// ~1.2e-4 worst-case near s=0), built PER BLOCK inside the single kernel so
// there is exactly one dispatch. Table entries reproduce the reference's
// 64-node Gauss-Legendre quadrature sum (nodes via 3-iter fp64 Newton).
//
// Reference step (fp32):
//   s     = 1.44*k^2 + 0.64*u^2
//   gi    = quad(s)
//   k_new = 0.8*k + gi*(0.18*k + 0.1*v)
//   v_new = 0.8*v + 0.2*u
//   z     = 0.7*gi*k_new

#define NG      514     // g samples: s = j/16, j = 0..513  (s in [0, 32.06])
#define NQ      511     // overlapping quads q[i] = g[i..i+3]
#define W_STEPS 64      // warm-up steps
#define CHUNK   8       // z outputs per thread
#define THREADS 256

// Per-step critical chain: fma(k^2) -> min -> max -> cvt -> add -> lshl ->
// ds_read_b128 -> 3-deep fma tree -> fma(k_new)  (~170 cy). Cubic weights,
// u^2 term, th, v, z are all off-chain (compute during the LDS read).
__device__ __forceinline__ float stepf(float& k, float& v, float uu,
                                       const float4* q) {
  float x  = fminf(fmaf(23.04f * k, k, 10.24f * uu * uu), 511.9f); // 16*s
  float xc = fmaxf(x, 1.0f);
  int   b  = (int)xc - 1;                  // stencil base, in [0, 510]
  float t  = x - (float)b;                 // in [0, 3); known before read
  float4 g = q[b];                         // one ds_read_b128
  float t1 = t - 1.0f, t2 = t - 2.0f, t3 = t - 3.0f;
  float p23 = t2 * t3, p01 = t * t1;
  float w0 = p23 * t1 * (-1.0f / 6.0f);    // Lagrange on nodes {0,1,2,3}
  float w1 = p23 * t  * 0.5f;
  float w2 = p01 * t3 * (-0.5f);
  float w3 = p01 * t2 * (1.0f / 6.0f);
  float gi = fmaf(w0, g.x, w1 * g.y) + fmaf(w2, g.z, w3 * g.w);
  float th = fmaf(0.18f, k, 0.1f * v);     // parallel to lookup
  float kn = fmaf(gi, th, 0.8f * k);
  v = fmaf(0.2f, uu, 0.8f * v);
  k = kn;
  return 0.7f * gi * kn;
}

__global__ __launch_bounds__(THREADS, 1) void scan1_kernel(
    const float* __restrict__ u, float* __restrict__ out) {
  __shared__ float  g_raw[NG];
  __shared__ float4 q[512];
  __shared__ float  zf[64], wf[64];
  __shared__ double aj[65], bj[65];

  const int tid    = threadIdx.x;
  const int t      = blockIdx.x * THREADS + tid;   // chunk id
  const int g8     = t * CHUNK;                    // first z index
  const int wsteps = min(W_STEPS, g8);             // multiple of 4
  const int ngrp   = wsteps >> 2;
  const float4* __restrict__ up = (const float4*)(u + (g8 - wsteps));

  float4 cur = up[0];            // issue early: HBM latency hides under build
  if (t == 0) out[0] = 0.0f;     // z_hist[0] = 0

  // ---- Gauss-Legendre order-64 nodes: 3-iter fp64 Newton on P_64 ----------
  if (tid >= 2 && tid <= 64) {
    double dj = (double)tid;
    aj[tid] = (2.0 * dj - 1.0) / dj;
    bj[tid] = (dj - 1.0) / dj;
  }
  __syncthreads();
  if (tid < 64) {
    double x = cos(3.14159265358979323846 * ((double)tid + 0.75) / 64.5);
    double dp = 1.0;
    for (int it = 0; it < 3; ++it) {
      double p0 = 1.0, p1 = x;
      for (int j = 2; j <= 64; ++j) {
        double p2 = fma(aj[j] * x, p1, -(bj[j] * p0));
        p0 = p1; p1 = p2;
      }
      dp = 64.0 * (x * p1 - p0) / (x * x - 1.0);
      x -= p1 / dp;
    }
    double w = 2.0 / ((1.0 - x * x) * dp * dp);
    // Match reference: nodes/weights scaled by A=5, cast to fp32.
    float zn = (float)(5.0 * x);
    float wn = (float)(5.0 * w);
    zf[tid] = zn;
    // fold weight * exp(-z^2/2) / (2*pi) into one fp32 coefficient
    wf[tid] = (float)((double)wn * exp(-0.5 * (double)zn * (double)zn)
                      * 0.15915494309189535);
  }
  __syncthreads();

  // ---- table: g[j] = sum_n wf[n] * sech^2(sqrt(j/16) * zf[n]) -------------
  for (int j = tid; j < NG; j += THREADS) {
    float d2 = 2.0f * sqrtf((float)j * (1.0f / 16.0f));
    float acc = 0.0f;
#pragma unroll 16
    for (int n = 0; n < 64; ++n) {
      float e  = __expf(-fabsf(d2 * zf[n]));   // sech^2 = 4e/(1+e)^2
      float tt = 1.0f + e;
      acc = fmaf(wf[n], 4.0f * e / (tt * tt), acc);
    }
    g_raw[j] = acc;
  }
  __syncthreads();
  for (int i = tid; i < NQ; i += THREADS)
    q[i] = make_float4(g_raw[i], g_raw[i + 1], g_raw[i + 2], g_raw[i + 3]);
  __syncthreads();

  // ---- warm-up: converge state from (0,0) over wsteps inputs --------------
  float k = 0.0f, v = 0.0f;
  for (int g = 0; g < ngrp; ++g) {
    float4 nxt = up[g + 1];                 // prefetch next 4 inputs
    stepf(k, v, cur.x, q);
    stepf(k, v, cur.y, q);
    stepf(k, v, cur.z, q);
    stepf(k, v, cur.w, q);
    cur = nxt;
  }

  // ---- emit CHUNK=8 outputs ----------------------------------------------
  float4 nxt = up[ngrp + 1];
  float z0 = stepf(k, v, cur.x, q);
  float z1 = stepf(k, v, cur.y, q);
  float z2 = stepf(k, v, cur.z, q);
  float z3 = stepf(k, v, cur.w, q);
  cur = nxt;
  float z4 = stepf(k, v, cur.x, q);
  float z5 = stepf(k, v, cur.y, q);
  float z6 = stepf(k, v, cur.z, q);
  float z7 = stepf(k, v, cur.w, q);
  out[g8 + 1] = z0;
  out[g8 + 2] = z1;
  out[g8 + 3] = z2;
  out[g8 + 4] = z3;
  out[g8 + 5] = z4;
  out[g8 + 6] = z5;
  out[g8 + 7] = z6;
  out[g8 + 8] = z7;
}

extern "C" void kernel_launch(void* const* d_in, const int* in_sizes, int n_in,
                              void* d_out, int out_size, void* d_ws,
                              size_t ws_size, hipStream_t stream) {
  const float* u = (const float*)d_in[0];
  float* out = (float*)d_out;
  const int T = in_sizes[0];                         // 524288
  const int nblock = T / (CHUNK * THREADS);          // 256
  scan1_kernel<<<nblock, THREADS, 0, stream>>>(u, out);
}

// Round 4
// 18.510 us; speedup vs baseline: 2.0816x; 1.2604x over previous
//
#include <hip/hip_runtime.h>

// OneDimEquivalent: T=524288-step contracting scan.
// Parallelization: warm-up windows (W=48, contraction <=0.88/step -> ~6e-5 z
// residual). gi(s), s=1.44k^2+0.64u^2, via 1024-cell linear table in x=32*s
// (h=1/32, interp err ~6e-5), with the *index* taken from the u-part only
// (known in advance -> LDS reads pipelined OFF the serial chain) and the k^2
// part applied analytically through the cell slope:
//   gi = [g0 + slope*frac(x_u)] + slope*46.08*k^2  = base_t + ck_t*k^2.
// Serial chain per step: k*k -> fma(gi) -> fma(kn): ~3 dependent VALU ops.
//
// Reference step (fp32):
//   k_new = 0.8*k + gi*(0.18*k + 0.1*v);  v_new = 0.8*v + 0.2*u;
//   z = 0.7*gi*k_new
// Table reproduces the reference's 64-node Gauss-Legendre sum (fp64 Newton
// nodes; symmetric pairs folded -> 32 evals/entry).

#define THREADS 256
#define CHUNK   8
#define W_STEPS 48
#define NSTEP   56            // W + CHUNK, 7 groups of 8
#define NCELL   1024          // x = 32*s over s in [0,32)

// prep: per-step table lookup + linearization constants (independent of k,v)
__device__ __forceinline__ void prep8(const float* uu, const float2* q,
                                      float* base, float* ck) {
#pragma unroll
  for (int j = 0; j < 8; ++j) {
    float x  = fminf(20.48f * uu[j] * uu[j], 1023.99f);  // 32 * 0.64 * u^2
    int   i  = (int)x;
    float fu = x - (float)i;
    float2 g = q[i];                    // (g[i], g[i+1]) one ds_read_b64
    float sl = g.y - g.x;
    base[j]  = fmaf(fu, sl, g.x);
    ck[j]    = 46.08f * sl;             // 32 * 1.44 per-k^2 slope
  }
}

// run: the serial recurrence; critical chain = mul,fma,fma per step
template <bool EMIT>
__device__ __forceinline__ void run8(const float* uu, const float* base,
                                     const float* ck, float& k, float& v,
                                     float* z) {
#pragma unroll
  for (int j = 0; j < 8; ++j) {
    float th = fmaf(0.18f, k, 0.1f * v);       // parallel to gi path
    float gi = fmaf(ck[j], k * k, base[j]);
    float kn = fmaf(gi, th, 0.8f * k);
    v = fmaf(0.2f, uu[j], 0.8f * v);
    if (EMIT) z[j] = 0.7f * gi * kn;
    k = kn;
  }
}

__global__ __launch_bounds__(THREADS, 1) void scan1_kernel(
    const float* __restrict__ u, float* __restrict__ out) {
  __shared__ float  graw[NCELL + 1];
  __shared__ float2 q[NCELL];
  __shared__ float  zf[64], wf[64], z2[32], w2[32];
  __shared__ double aj[65], bj[65];

  const int tid = threadIdx.x;
  const int t   = blockIdx.x * THREADS + tid;
  const int g8  = t * CHUNK;
  if (t == 0) out[0] = 0.0f;

  // ---- issue all u loads first: HBM latency hides under the table build ---
  const int base4 = (g8 - W_STEPS) >> 2;       // multiple of 2 (g8%8==0)
  const float4* __restrict__ up = (const float4*)u;
  float uu[NSTEP];
#pragma unroll
  for (int j = 0; j < NSTEP / 4; ++j) {
    int idx = base4 + j;
    float4 w = up[max(idx, 0)];
    bool ok = (idx >= 0);                       // first block: u=0 pre-history
    uu[4 * j + 0] = ok ? w.x : 0.0f;
    uu[4 * j + 1] = ok ? w.y : 0.0f;
    uu[4 * j + 2] = ok ? w.z : 0.0f;
    uu[4 * j + 3] = ok ? w.w : 0.0f;
  }

  // ---- Gauss-Legendre order-64 nodes: 3-iter fp64 Newton on P_64 ----------
  if (tid >= 2 && tid <= 64) {
    double dj = (double)tid;
    aj[tid] = (2.0 * dj - 1.0) / dj;
    bj[tid] = (dj - 1.0) / dj;
  }
  __syncthreads();
  if (tid < 64) {
    double x = cos(3.14159265358979323846 * ((double)tid + 0.75) / 64.5);
    double dp = 1.0;
    for (int it = 0; it < 3; ++it) {
      double p0 = 1.0, p1 = x;
      for (int j = 2; j <= 64; ++j) {
        double p2 = fma(aj[j] * x, p1, -(bj[j] * p0));
        p0 = p1; p1 = p2;
      }
      dp = 64.0 * (x * p1 - p0) / (x * x - 1.0);
      x -= p1 / dp;
    }
    double w = 2.0 / ((1.0 - x * x) * dp * dp);
    float zn = (float)(5.0 * x);                // match reference: A=5, fp32
    float wn = (float)(5.0 * w);
    zf[tid] = zn;
    wf[tid] = (float)((double)wn * exp(-0.5 * (double)zn * (double)zn)
                      * 0.15915494309189535);   // w*exp(-z^2/2)/(2*pi)
  }
  __syncthreads();
  if (tid < 32) {                               // fold symmetric node pairs
    z2[tid] = zf[tid];                          // tid<32 -> positive roots
    w2[tid] = wf[tid] + wf[63 - tid];
  }
  __syncthreads();

  // ---- table: g[j] = sum_n w2[n] * sech^2(sqrt(j/32)*z2[n]) ---------------
  for (int j = tid; j <= NCELL; j += THREADS) {
    float d2 = 2.0f * sqrtf((float)j * (1.0f / 32.0f));
    float acc = 0.0f;
#pragma unroll
    for (int n = 0; n < 32; ++n) {
      float e  = __expf(-d2 * z2[n]);           // sech^2 = 4e/(1+e)^2
      float tt = 1.0f + e;
      acc = fmaf(w2[n], 4.0f * e / (tt * tt), acc);
    }
    graw[j] = acc;
  }
  __syncthreads();
  for (int i = tid; i < NCELL; i += THREADS)
    q[i] = make_float2(graw[i], graw[i + 1]);
  __syncthreads();

  // ---- scan: 7 groups of 8 steps, lookups pipelined 2 groups ahead --------
  float k = 0.0f, v = 0.0f, z[8];
  float B0[8], C0[8], B1[8], C1[8];
  prep8(uu + 0,  q, B0, C0);
  prep8(uu + 8,  q, B1, C1);
  run8<false>(uu + 0,  B0, C0, k, v, z);
  prep8(uu + 16, q, B0, C0);
  run8<false>(uu + 8,  B1, C1, k, v, z);
  prep8(uu + 24, q, B1, C1);
  run8<false>(uu + 16, B0, C0, k, v, z);
  prep8(uu + 32, q, B0, C0);
  run8<false>(uu + 24, B1, C1, k, v, z);
  prep8(uu + 40, q, B1, C1);
  run8<false>(uu + 32, B0, C0, k, v, z);
  prep8(uu + 48, q, B0, C0);
  run8<false>(uu + 40, B1, C1, k, v, z);
  run8<true>(uu + 48, B0, C0, k, v, z);

#pragma unroll
  for (int j = 0; j < 8; ++j) out[g8 + 1 + j] = z[j];
}

extern "C" void kernel_launch(void* const* d_in, const int* in_sizes, int n_in,
                              void* d_out, int out_size, void* d_ws,
                              size_t ws_size, hipStream_t stream) {
  const float* u = (const float*)d_in[0];
  float* out = (float*)d_out;
  const int T = in_sizes[0];                    // 524288
  const int nblock = T / (CHUNK * THREADS);     // 256
  scan1_kernel<<<nblock, THREADS, 0, stream>>>(u, out);
}

// Round 5
// 16.665 us; speedup vs baseline: 2.3120x; 1.1107x over previous
//
#include <hip/hip_runtime.h>

// OneDimEquivalent: T=524288-step contracting scan, single dispatch.
// Parallelization: warm-up windows (W=48; contraction <=0.872/step -> ~1.5e-4
// z residual). gi(s), s = 1.44k^2 + 0.64u^2, via 1024-cell linear LDS table
// in x = 32*s; the table INDEX comes from the u-part only (known in advance,
// so all LDS gathers pipeline OFF the serial chain) and the k^2 part is
// applied through the cell slope:  gi = base_t + ck_t*k^2.
// Serial chain per step: k*k -> fma -> fma (~3 dependent VALU ops).
//
// Table reproduces the reference's 64-node Gauss-Legendre fp32 quadrature
// (NOT the true integral -- G-L 64 differs from it by ~2e-4 at large delta,
// which is the observed absmax floor). Nodes: 3 fp32 Newton iterations on
// P_64 + one fp64 polish (cheaper than all-fp64; node err ~1e-9).
//
// Measured harness floor ~15 us/replay; kernel-internal time is build-
// dominated (~2-3 us). This round cuts the fp64 Newton chain 189->63 FMAs
// and the table-fill divide (IEEE div -> v_rcp_f32).

#define THREADS 256
#define CHUNK   8
#define W_STEPS 48
#define NSTEP   56            // W + CHUNK, 7 groups of 8
#define NCELL   1024          // x = 32*s over s in [0,32)

#if __has_builtin(__builtin_amdgcn_rcpf)
#define RCPF(x) __builtin_amdgcn_rcpf(x)
#else
#define RCPF(x) (1.0f / (x))
#endif

// prep: per-step table lookup + linearization constants (independent of k,v)
__device__ __forceinline__ void prep8(const float* uu, const float2* q,
                                      float* base, float* ck) {
#pragma unroll
  for (int j = 0; j < 8; ++j) {
    float x  = fminf(20.48f * uu[j] * uu[j], 1023.99f);  // 32 * 0.64 * u^2
    int   i  = (int)x;
    float fu = x - (float)i;
    float2 g = q[i];                    // (g[i], g[i+1]) one ds_read_b64
    float sl = g.y - g.x;
    base[j]  = fmaf(fu, sl, g.x);
    ck[j]    = 46.08f * sl;             // 32 * 1.44 per-k^2 slope
  }
}

// run: the serial recurrence; critical chain = mul,fma,fma per step
template <bool EMIT>
__device__ __forceinline__ void run8(const float* uu, const float* base,
                                     const float* ck, float& k, float& v,
                                     float* z) {
#pragma unroll
  for (int j = 0; j < 8; ++j) {
    float th = fmaf(0.18f, k, 0.1f * v);       // parallel to gi path
    float gi = fmaf(ck[j], k * k, base[j]);
    float kn = fmaf(gi, th, 0.8f * k);
    v = fmaf(0.2f, uu[j], 0.8f * v);
    if (EMIT) z[j] = 0.7f * gi * kn;
    k = kn;
  }
}

__global__ __launch_bounds__(THREADS, 1) void scan1_kernel(
    const float* __restrict__ u, float* __restrict__ out) {
  __shared__ float  graw[NCELL + 1];
  __shared__ float2 q[NCELL];
  __shared__ float  z2[32], w2[32];
  __shared__ float  zf[64], wf[64];
  __shared__ float  aj32[65], bj32[65];
  __shared__ double aj[65], bj[65];

  const int tid = threadIdx.x;
  const int t   = blockIdx.x * THREADS + tid;
  const int g8  = t * CHUNK;
  if (t == 0) out[0] = 0.0f;

  // ---- issue all u loads first: HBM latency hides under the table build ---
  const int base4 = (g8 - W_STEPS) >> 2;
  const float4* __restrict__ up = (const float4*)u;
  float uu[NSTEP];
#pragma unroll
  for (int j = 0; j < NSTEP / 4; ++j) {
    int idx = base4 + j;
    float4 w = up[max(idx, 0)];
    bool ok = (idx >= 0);                       // first block: u=0 pre-history
    uu[4 * j + 0] = ok ? w.x : 0.0f;
    uu[4 * j + 1] = ok ? w.y : 0.0f;
    uu[4 * j + 2] = ok ? w.z : 0.0f;
    uu[4 * j + 3] = ok ? w.w : 0.0f;
  }

  // ---- recurrence coefficients for P_64 ------------------------------------
  if (tid >= 2 && tid <= 64) {
    double dj = (double)tid;
    double a = (2.0 * dj - 1.0) / dj;
    double b = (dj - 1.0) / dj;
    aj[tid] = a;  bj[tid] = b;
    aj32[tid] = (float)a;  bj32[tid] = (float)b;
  }
  __syncthreads();

  // ---- Gauss-Legendre nodes: 3 fp32 Newton iters + 1 fp64 polish -----------
  if (tid < 64) {
    float xf = __cosf(3.14159265f * ((float)tid + 0.75f) / 64.5f);
#pragma unroll
    for (int it = 0; it < 3; ++it) {            // fp32: converge to ~1e-7
      float p0 = 1.0f, p1 = xf;
      for (int j = 2; j <= 64; ++j) {
        float p2 = fmaf(aj32[j] * xf, p1, -(bj32[j] * p0));
        p0 = p1; p1 = p2;
      }
      float dpf = 64.0f * (xf * p1 - p0) / (xf * xf - 1.0f);
      xf -= p1 / dpf;
    }
    double x = (double)xf;                      // fp64 polish: -> ~1e-9
    double p0 = 1.0, p1 = x;
    for (int j = 2; j <= 64; ++j) {
      double p2 = fma(aj[j] * x, p1, -(bj[j] * p0));
      p0 = p1; p1 = p2;
    }
    double dp = 64.0 * (x * p1 - p0) / (x * x - 1.0);
    double w  = 2.0 / ((1.0 - x * x) * dp * dp);
    x -= p1 / dp;
    // Match reference: nodes/weights scaled by A=5, cast to fp32.
    float zn = (float)(5.0 * x);
    float wn = (float)(5.0 * w);
    zf[tid] = zn;
    // fold weight * exp(-z^2/2) / (2*pi) (fp32 fold: rel err ~1e-7, ample)
    wf[tid] = wn * __expf(-0.5f * zn * zn) * 0.15915494309189535f;
  }
  __syncthreads();
  if (tid < 32) {                               // fold symmetric node pairs
    z2[tid] = zf[tid];                          // tid<32 -> positive roots
    w2[tid] = wf[tid] + wf[63 - tid];
  }
  __syncthreads();

  // ---- table: g[j] = sum_n w2[n] * sech^2(sqrt(j/32)*z2[n]) ---------------
  for (int j = tid; j <= NCELL; j += THREADS) {
    float d2 = 2.0f * sqrtf((float)j * (1.0f / 32.0f));
    float acc = 0.0f;
#pragma unroll
    for (int n = 0; n < 32; ++n) {
      float e = __expf(-d2 * z2[n]);            // sech^2 = 4e/(1+e)^2
      float r = RCPF(1.0f + e);                 // v_rcp_f32, 1 ulp
      acc = fmaf(w2[n], 4.0f * e * r * r, acc);
    }
    graw[j] = acc;
  }
  __syncthreads();
  for (int i = tid; i < NCELL; i += THREADS)
    q[i] = make_float2(graw[i], graw[i + 1]);
  __syncthreads();

  // ---- scan: 7 groups of 8 steps, lookups pipelined 2 groups ahead --------
  float k = 0.0f, v = 0.0f, z[8];
  float B0[8], C0[8], B1[8], C1[8];
  prep8(uu + 0,  q, B0, C0);
  prep8(uu + 8,  q, B1, C1);
  run8<false>(uu + 0,  B0, C0, k, v, z);
  prep8(uu + 16, q, B0, C0);
  run8<false>(uu + 8,  B1, C1, k, v, z);
  prep8(uu + 24, q, B1, C1);
  run8<false>(uu + 16, B0, C0, k, v, z);
  prep8(uu + 32, q, B0, C0);
  run8<false>(uu + 24, B1, C1, k, v, z);
  prep8(uu + 40, q, B1, C1);
  run8<false>(uu + 32, B0, C0, k, v, z);
  prep8(uu + 48, q, B0, C0);
  run8<false>(uu + 40, B1, C1, k, v, z);
  run8<true>(uu + 48, B0, C0, k, v, z);

#pragma unroll
  for (int j = 0; j < 8; ++j) out[g8 + 1 + j] = z[j];
}

extern "C" void kernel_launch(void* const* d_in, const int* in_sizes, int n_in,
                              void* d_out, int out_size, void* d_ws,
                              size_t ws_size, hipStream_t stream) {
  const float* u = (const float*)d_in[0];
  float* out = (float*)d_out;
  const int T = in_sizes[0];                    // 524288
  const int nblock = T / (CHUNK * THREADS);     // 256
  scan1_kernel<<<nblock, THREADS, 0, stream>>>(u, out);
}

// Round 6
// 13.079 us; speedup vs baseline: 2.9461x; 1.2743x over previous
//
#include <hip/hip_runtime.h>

// OneDimEquivalent: T=524288-step contracting scan, single dispatch.
// Parallelization: warm-up windows (W=40; contraction <=0.872/step and
// |k|<~0.08 -> ~1e-4 z residual). gi(s), s = 1.44k^2 + 0.64u^2, via a
// TWO-RESOLUTION linear LDS table (G'' ~ 1.6 at s=0, ~s^-5/2 decay):
//   region A: s in [0,4),    h=1/32, 128 cells  (err ~2e-4 only at s~0,
//                                                suppressed in z by |k|)
//   region B: s in [4,20.5), h=1/4,   66 cells  (err ~5e-5)
// 196 samples = ONE table entry per thread (fill was the dominant cost at
// 1 wave/SIMD). Index comes from the u-part only (known in advance -> LDS
// gathers pipeline OFF the serial chain); k^2 applied via the cell slope:
// gi = base_t + ck_t*k^2. Serial chain: k*k -> fma -> fma per step.
//
// Table reproduces the reference's 64-node Gauss-Legendre fp32 quadrature
// (G-L 64 vs true integral differs ~2e-4 at large delta = observed absmax
// floor). Nodes: 2 fp32 Newton iters on P_64 + one fp64 polish.

#define THREADS 256
#define CHUNK   8
#define W_STEPS 40
#define NSTEP   48            // W + CHUNK, 6 groups of 8
#define NA      129           // region A samples: s = j/32,     j = 0..128
#define NB      67            // region B samples: s = 4 + j/4,  j = 0..66
#define NENT    (NA + NB)     // 196 table samples (one per thread)
#define NQA     128           // region A cells
#define NQ      194           // total cells (A:0..127, B:128..193)

#if __has_builtin(__builtin_amdgcn_rcpf)
#define RCPF(x) __builtin_amdgcn_rcpf(x)
#else
#define RCPF(x) (1.0f / (x))
#endif

// prep: per-step table lookup + linearization constants (independent of k,v)
__device__ __forceinline__ void prep8(const float* uu, const float2* q,
                                      float* base, float* ck) {
#pragma unroll
  for (int j = 0; j < 8; ++j) {
    float u2 = uu[j] * uu[j];
    float xA = 20.48f * u2;                     // 32 * 0.64 * u^2
    bool  inA = xA < 128.0f;
    float xB = fminf(fmaf(2.56f, u2, -16.0f), 65.95f) + 128.0f;
    float x  = inA ? xA : xB;
    int   i  = (int)x;
    float f  = x - (float)i;
    float2 g = q[i];                            // one ds_read_b64
    float sl = g.y - g.x;
    base[j]  = fmaf(f, sl, g.x);
    ck[j]    = (inA ? 46.08f : 5.76f) * sl;     // 1.44 / h_region per-k^2
  }
}

// run: the serial recurrence; critical chain = mul,fma,fma per step
template <bool EMIT>
__device__ __forceinline__ void run8(const float* uu, const float* base,
                                     const float* ck, float& k, float& v,
                                     float* z) {
#pragma unroll
  for (int j = 0; j < 8; ++j) {
    float th = fmaf(0.18f, k, 0.1f * v);        // parallel to gi path
    float gi = fmaf(ck[j], k * k, base[j]);
    float kn = fmaf(gi, th, 0.8f * k);
    v = fmaf(0.2f, uu[j], 0.8f * v);
    if (EMIT) z[j] = 0.7f * gi * kn;
    k = kn;
  }
}

__global__ __launch_bounds__(THREADS, 1) void scan1_kernel(
    const float* __restrict__ u, float* __restrict__ out) {
  __shared__ float  graw[NENT];
  __shared__ float2 q[NQ];
  __shared__ float  z2[32], w2[32];
  __shared__ float  zf[64], wf[64];
  __shared__ float  aj32[65], bj32[65];
  __shared__ double aj[65], bj[65];

  const int tid = threadIdx.x;
  const int t   = blockIdx.x * THREADS + tid;
  const int g8  = t * CHUNK;
  if (t == 0) out[0] = 0.0f;

  // ---- issue all u loads first: HBM latency hides under the table build ---
  const int base4 = (g8 - W_STEPS) >> 2;
  const float4* __restrict__ up = (const float4*)u;
  float uu[NSTEP];
#pragma unroll
  for (int j = 0; j < NSTEP / 4; ++j) {
    int idx = base4 + j;
    float4 w = up[max(idx, 0)];
    bool ok = (idx >= 0);                       // first block: u=0 pre-history
    uu[4 * j + 0] = ok ? w.x : 0.0f;
    uu[4 * j + 1] = ok ? w.y : 0.0f;
    uu[4 * j + 2] = ok ? w.z : 0.0f;
    uu[4 * j + 3] = ok ? w.w : 0.0f;
  }

  // ---- recurrence coefficients for P_64 ------------------------------------
  if (tid >= 2 && tid <= 64) {
    double dj = (double)tid;
    double a = (2.0 * dj - 1.0) / dj;
    double b = (dj - 1.0) / dj;
    aj[tid] = a;  bj[tid] = b;
    aj32[tid] = (float)a;  bj32[tid] = (float)b;
  }
  __syncthreads();

  // ---- Gauss-Legendre nodes: 2 fp32 Newton iters + 1 fp64 polish -----------
  if (tid < 64) {
    float xf = __cosf(3.14159265f * ((float)tid + 0.75f) / 64.5f);
#pragma unroll
    for (int it = 0; it < 2; ++it) {            // fp32: converge to ~1e-7
      float p0 = 1.0f, p1 = xf;
      for (int j = 2; j <= 64; ++j) {
        float p2 = fmaf(aj32[j] * xf, p1, -(bj32[j] * p0));
        p0 = p1; p1 = p2;
      }
      float dpf = 64.0f * (xf * p1 - p0) / (xf * xf - 1.0f);
      xf -= p1 / dpf;
    }
    double x = (double)xf;                      // fp64 polish
    double p0 = 1.0, p1 = x;
    for (int j = 2; j <= 64; ++j) {
      double p2 = fma(aj[j] * x, p1, -(bj[j] * p0));
      p0 = p1; p1 = p2;
    }
    double dp = 64.0 * (x * p1 - p0) / (x * x - 1.0);
    double w  = 2.0 / ((1.0 - x * x) * dp * dp);
    x -= p1 / dp;
    // Match reference: nodes/weights scaled by A=5, cast to fp32.
    float zn = (float)(5.0 * x);
    float wn = (float)(5.0 * w);
    zf[tid] = zn;
    // fold weight * exp(-z^2/2) / (2*pi)
    wf[tid] = wn * __expf(-0.5f * zn * zn) * 0.15915494309189535f;
  }
  __syncthreads();
  if (tid < 32) {                               // fold symmetric node pairs
    z2[tid] = zf[tid];                          // tid<32 -> positive roots
    w2[tid] = wf[tid] + wf[63 - tid];
  }
  __syncthreads();

  // ---- table: one sample per thread ---------------------------------------
  if (tid < NENT) {
    float s = (tid < NA) ? (float)tid * (1.0f / 32.0f)
                         : fmaf((float)(tid - NA), 0.25f, 4.0f);
    float d2 = 2.0f * sqrtf(s);
    float acc = 0.0f;
#pragma unroll
    for (int n = 0; n < 32; ++n) {
      float e = __expf(-d2 * z2[n]);            // sech^2 = 4e/(1+e)^2
      float r = RCPF(1.0f + e);                 // v_rcp_f32, 1 ulp
      acc = fmaf(w2[n], 4.0f * e * r * r, acc);
    }
    graw[tid] = acc;
  }
  __syncthreads();
  if (tid < NQ) {
    int sbase = (tid < NQA) ? tid : tid + 1;    // B samples start at graw[129]
    q[tid] = make_float2(graw[sbase], graw[sbase + 1]);
  }
  __syncthreads();

  // ---- scan: 6 groups of 8 steps, lookups pipelined 2 groups ahead --------
  float k = 0.0f, v = 0.0f, z[8];
  float B0[8], C0[8], B1[8], C1[8];
  prep8(uu + 0,  q, B0, C0);
  prep8(uu + 8,  q, B1, C1);
  run8<false>(uu + 0,  B0, C0, k, v, z);
  prep8(uu + 16, q, B0, C0);
  run8<false>(uu + 8,  B1, C1, k, v, z);
  prep8(uu + 24, q, B1, C1);
  run8<false>(uu + 16, B0, C0, k, v, z);
  prep8(uu + 32, q, B0, C0);
  run8<false>(uu + 24, B1, C1, k, v, z);
  prep8(uu + 40, q, B1, C1);
  run8<false>(uu + 32, B0, C0, k, v, z);
  run8<true>(uu + 40, B1, C1, k, v, z);

#pragma unroll
  for (int j = 0; j < 8; ++j) out[g8 + 1 + j] = z[j];
}

extern "C" void kernel_launch(void* const* d_in, const int* in_sizes, int n_in,
                              void* d_out, int out_size, void* d_ws,
                              size_t ws_size, hipStream_t stream) {
  const float* u = (const float*)d_in[0];
  float* out = (float*)d_out;
  const int T = in_sizes[0];                    // 524288
  const int nblock = T / (CHUNK * THREADS);     // 256
  scan1_kernel<<<nblock, THREADS, 0, stream>>>(u, out);
}

// Round 7
// 10.557 us; speedup vs baseline: 3.6498x; 1.2389x over previous
//
#include <hip/hip_runtime.h>

// OneDimEquivalent: T=524288-step contracting scan, single dispatch.
// Parallelization: warm-up windows (W=40; contraction <=0.872/step ->
// ~1.6e-4 state residual, ~1e-4 in z). gi(s), s = 1.44k^2 + 0.64u^2, via a
// two-resolution linear LDS table (region A: s in [0,4), h=1/32, 128 cells;
// region B: s in [4,20.5), h=1/4, 66 cells). Index comes from the u-part
// only (known in advance -> LDS gathers pipeline OFF the serial chain); the
// k^2 part is applied via the cell slope: gi = base_t + ck_t*k^2.
// Serial chain per step: k*k -> fma -> fma.
//
// NEW this round: the whole table (G-L 64 nodes via 5-iter fp64 Newton on
// P_64, fp32 casts exactly where the reference casts, folded symmetric
// pairs, sech^2 quadrature sum) is evaluated at COMPILE TIME (constexpr)
// and baked into .rodata. The kernel has no build phase left: copy 194
// float2 cells to LDS, one barrier, scan. (R6 measured the on-device build
// at ~0.5-1 us plus 3 barriers; harness replay floor is ~12-13 us.)

#define THREADS 256
#define CHUNK   8
#define W_STEPS 40
#define NSTEP   48            // W + CHUNK, 6 groups of 8
#define NA      129           // region A samples: s = j/32,     j = 0..128
#define NB      67            // region B samples: s = 4 + j/4,  j = 0..66
#define NQA     128           // region A cells
#define NQ      194           // total cells (A:0..127, B:128..193)

// ---------------- compile-time math (fp64, constexpr) -----------------------
constexpr double CPI  = 3.14159265358979323846;
constexpr double CLN2H = 0.6931471805599453;
constexpr double CLN2L = 2.3190468138462996e-17;
constexpr double CL2E  = 1.4426950408889634;

constexpr double cexp(double x) {            // x <= 0, |x| < 700
  int n = (int)(x * CL2E - 0.5);             // round-to-nearest (x<=0)
  double r = (x - n * CLN2H) - n * CLN2L;
  double acc = 1.0, term = 1.0;
  for (int k = 1; k <= 13; ++k) { term *= r / k; acc += term; }
  double s = 1.0, b = 2.0;
  int m = -n;                                // n <= 0
  while (m) { if (m & 1) s *= b; b *= b; m >>= 1; }
  return acc / s;
}
constexpr double ccos(double x) {            // |x| <= pi
  double x2 = x * x, acc = 1.0, term = 1.0;
  for (int k = 1; k <= 12; ++k) {
    term *= -x2 / ((2.0 * k - 1.0) * (2.0 * k));
    acc += term;
  }
  return acc;
}
constexpr double csqrt(double s) {           // s in [0, 64)
  if (s <= 0.0) return 0.0;
  double r = s > 1.0 ? s : 1.0;
  for (int it = 0; it < 20; ++it) r = 0.5 * (r + s / r);
  return r;
}

// Gauss-Legendre order 64: positive nodes + folded pair weights, with fp32
// casts exactly where the reference casts (nodes/weights scaled by A=5).
struct GL32 { double z[32]; double w2[32]; };
constexpr GL32 make_gl() {
  GL32 g{};
  for (int i = 0; i < 32; ++i) {
    double x = ccos(CPI * ((double)i + 0.75) / 64.5);
    double dp = 1.0;
    for (int it = 0; it < 5; ++it) {         // Newton on P_64, fp64
      double p0 = 1.0, p1 = x;
      for (int j = 2; j <= 64; ++j) {
        double p2 = ((2.0 * j - 1.0) * x * p1 - (double)(j - 1) * p0) / j;
        p0 = p1; p1 = p2;
      }
      dp = 64.0 * (x * p1 - p0) / (x * x - 1.0);
      x -= p1 / dp;
    }
    double w = 2.0 / ((1.0 - x * x) * dp * dp);
    float zn = (float)(5.0 * x);             // reference: fp32 node
    float wn = (float)(5.0 * w);             // reference: fp32 weight
    g.z[i]  = (double)zn;
    // folded +/- pair: 2 * w * exp(-z^2/2) / (2*pi)
    g.w2[i] = 2.0 * (double)wn * cexp(-0.5 * (double)zn * (double)zn)
              * 0.15915494309189535;
  }
  return g;
}
constexpr GL32 GLC = make_gl();

// g(s) = sum_n w2[n] * sech^2(sqrt(s)*z[n]);  sech^2(a) = 4e/(1+e)^2,
// e = exp(-2a). Cutoff a>12.5 (contribution <1e-10; fp32 tanh saturates
// at a>9 in the reference anyway).
constexpr float tab_entry(double s) {
  double d2 = 2.0 * csqrt(s);
  double acc = 0.0;
  for (int n = 0; n < 32; ++n) {
    double a = d2 * GLC.z[n];
    if (a < 12.5) {
      double e = cexp(-a);
      double t = 1.0 + e;
      acc += GLC.w2[n] * (4.0 * e / (t * t));
    }
  }
  return (float)acc;
}
struct TabA { float g[NA]; };
struct TabB { float g[NB]; };
constexpr TabA make_tabA() {
  TabA t{};
  for (int j = 0; j < NA; ++j) t.g[j] = tab_entry((double)j * (1.0 / 32.0));
  return t;
}
constexpr TabB make_tabB() {
  TabB t{};
  for (int j = 0; j < NB; ++j) t.g[j] = tab_entry(4.0 + (double)j * 0.25);
  return t;
}
__device__ constexpr TabA TA = make_tabA();
__device__ constexpr TabB TB = make_tabB();

// ---------------- scan pieces (identical to R6) -----------------------------
// prep: per-step table lookup + linearization constants (independent of k,v)
__device__ __forceinline__ void prep8(const float* uu, const float2* q,
                                      float* base, float* ck) {
#pragma unroll
  for (int j = 0; j < 8; ++j) {
    float u2 = uu[j] * uu[j];
    float xA = 20.48f * u2;                     // 32 * 0.64 * u^2
    bool  inA = xA < 128.0f;
    float xB = fminf(fmaf(2.56f, u2, -16.0f), 65.95f) + 128.0f;
    float x  = inA ? xA : xB;
    int   i  = (int)x;
    float f  = x - (float)i;
    float2 g = q[i];                            // one ds_read_b64
    float sl = g.y - g.x;
    base[j]  = fmaf(f, sl, g.x);
    ck[j]    = (inA ? 46.08f : 5.76f) * sl;     // 1.44 / h_region per-k^2
  }
}
// run: the serial recurrence; critical chain = mul,fma,fma per step
template <bool EMIT>
__device__ __forceinline__ void run8(const float* uu, const float* base,
                                     const float* ck, float& k, float& v,
                                     float* z) {
#pragma unroll
  for (int j = 0; j < 8; ++j) {
    float th = fmaf(0.18f, k, 0.1f * v);        // parallel to gi path
    float gi = fmaf(ck[j], k * k, base[j]);
    float kn = fmaf(gi, th, 0.8f * k);
    v = fmaf(0.2f, uu[j], 0.8f * v);
    if (EMIT) z[j] = 0.7f * gi * kn;
    k = kn;
  }
}

__global__ __launch_bounds__(THREADS, 1) void scan1_kernel(
    const float* __restrict__ u, float* __restrict__ out) {
  __shared__ float2 q[NQ];

  const int tid = threadIdx.x;
  const int t   = blockIdx.x * THREADS + tid;
  const int g8  = t * CHUNK;
  if (t == 0) out[0] = 0.0f;

  // ---- issue all u loads first --------------------------------------------
  const int base4 = (g8 - W_STEPS) >> 2;
  const float4* __restrict__ up = (const float4*)u;
  float uu[NSTEP];
#pragma unroll
  for (int j = 0; j < NSTEP / 4; ++j) {
    int idx = base4 + j;
    float4 w = up[max(idx, 0)];
    bool ok = (idx >= 0);                       // first block: u=0 pre-history
    uu[4 * j + 0] = ok ? w.x : 0.0f;
    uu[4 * j + 1] = ok ? w.y : 0.0f;
    uu[4 * j + 2] = ok ? w.z : 0.0f;
    uu[4 * j + 3] = ok ? w.w : 0.0f;
  }

  // ---- table: copy .rodata -> LDS (pairs never straddle regions) ----------
  if (tid < NQ) {
    float a, b;
    if (tid < NQA) { a = TA.g[tid];       b = TA.g[tid + 1]; }
    else           { int j = tid - NQA; a = TB.g[j]; b = TB.g[j + 1]; }
    q[tid] = make_float2(a, b);
  }
  __syncthreads();

  // ---- scan: 6 groups of 8 steps, lookups pipelined 2 groups ahead --------
  float k = 0.0f, v = 0.0f, z[8];
  float B0[8], C0[8], B1[8], C1[8];
  prep8(uu + 0,  q, B0, C0);
  prep8(uu + 8,  q, B1, C1);
  run8<false>(uu + 0,  B0, C0, k, v, z);
  prep8(uu + 16, q, B0, C0);
  run8<false>(uu + 8,  B1, C1, k, v, z);
  prep8(uu + 24, q, B1, C1);
  run8<false>(uu + 16, B0, C0, k, v, z);
  prep8(uu + 32, q, B0, C0);
  run8<false>(uu + 24, B1, C1, k, v, z);
  prep8(uu + 40, q, B1, C1);
  run8<false>(uu + 32, B0, C0, k, v, z);
  run8<true>(uu + 40, B1, C1, k, v, z);

#pragma unroll
  for (int j = 0; j < 8; ++j) out[g8 + 1 + j] = z[j];
}

extern "C" void kernel_launch(void* const* d_in, const int* in_sizes, int n_in,
                              void* d_out, int out_size, void* d_ws,
                              size_t ws_size, hipStream_t stream) {
  const float* u = (const float*)d_in[0];
  float* out = (float*)d_out;
  const int T = in_sizes[0];                    // 524288
  const int nblock = T / (CHUNK * THREADS);     // 256
  scan1_kernel<<<nblock, THREADS, 0, stream>>>(u, out);
}

// Round 8
// 9.937 us; speedup vs baseline: 3.8773x; 1.0623x over previous
//
#include <hip/hip_runtime.h>

// OneDimEquivalent: T=524288-step contracting scan, single dispatch.
// Parallelization: warm-up windows (W=40; contraction <=0.872/step ->
// ~1.3e-4 z residual). gi(s), s = 1.44k^2 + 0.64u^2, via a single-region
// linear LDS table: s in [0,20.5), h=1/16, 328 cells. Interp err ~7.8e-4 in
// G near s=0, but z-coupling is suppressed by |k|<~0.08 -> ~1e-4 in z.
// Index comes from the u-part only (known in advance -> LDS gathers pipeline
// OFF the serial chain); k^2 applied via the baked cell slope:
//   gi = base_t + ck_t*k^2,  ck = 1.44/h * slope  (pre-baked per cell).
// Serial chain per step: k*k -> fma -> fma.
//
// Table (G-L 64 nodes via 5-iter fp64 Newton on P_64, fp32 casts exactly
// where the reference casts, folded symmetric pairs, sech^2 quadrature) is
// fully evaluated at COMPILE TIME; cells are fat float4 (g0, slope, ck, 0)
// so prep8 is ~6 VALU + one ds_read_b128. Kernel: copy 328 cells to LDS,
// one barrier, scan.

#define THREADS 256
#define CHUNK   8
#define W_STEPS 40
#define NSTEP   48            // W + CHUNK, 6 groups of 8
#define NCELL   328           // x = 16*s over s in [0, 20.5)

#if __has_builtin(__builtin_amdgcn_fractf)
#define FRACTF(x) __builtin_amdgcn_fractf(x)
#else
#define FRACTF(x) ((x) - floorf(x))
#endif

// ---------------- compile-time math (fp64, constexpr) -----------------------
constexpr double CPI   = 3.14159265358979323846;
constexpr double CLN2H = 0.6931471805599453;
constexpr double CLN2L = 2.3190468138462996e-17;
constexpr double CL2E  = 1.4426950408889634;

constexpr double cexp(double x) {            // x <= 0, |x| < 700
  int n = (int)(x * CL2E - 0.5);             // round-to-nearest (x<=0)
  double r = (x - n * CLN2H) - n * CLN2L;
  double acc = 1.0, term = 1.0;
  for (int k = 1; k <= 13; ++k) { term *= r / k; acc += term; }
  double s = 1.0, b = 2.0;
  int m = -n;                                // n <= 0
  while (m) { if (m & 1) s *= b; b *= b; m >>= 1; }
  return acc / s;
}
constexpr double ccos(double x) {            // |x| <= pi
  double x2 = x * x, acc = 1.0, term = 1.0;
  for (int k = 1; k <= 12; ++k) {
    term *= -x2 / ((2.0 * k - 1.0) * (2.0 * k));
    acc += term;
  }
  return acc;
}
constexpr double csqrt(double s) {           // s in [0, 64)
  if (s <= 0.0) return 0.0;
  double r = s > 1.0 ? s : 1.0;
  for (int it = 0; it < 20; ++it) r = 0.5 * (r + s / r);
  return r;
}

// Gauss-Legendre order 64: positive nodes + folded pair weights, with fp32
// casts exactly where the reference casts (nodes/weights scaled by A=5).
struct GL32 { double z[32]; double w2[32]; };
constexpr GL32 make_gl() {
  GL32 g{};
  for (int i = 0; i < 32; ++i) {
    double x = ccos(CPI * ((double)i + 0.75) / 64.5);
    double dp = 1.0;
    for (int it = 0; it < 5; ++it) {         // Newton on P_64, fp64
      double p0 = 1.0, p1 = x;
      for (int j = 2; j <= 64; ++j) {
        double p2 = ((2.0 * j - 1.0) * x * p1 - (double)(j - 1) * p0) / j;
        p0 = p1; p1 = p2;
      }
      dp = 64.0 * (x * p1 - p0) / (x * x - 1.0);
      x -= p1 / dp;
    }
    double w = 2.0 / ((1.0 - x * x) * dp * dp);
    float zn = (float)(5.0 * x);             // reference: fp32 node
    float wn = (float)(5.0 * w);             // reference: fp32 weight
    g.z[i]  = (double)zn;
    // folded +/- pair: 2 * w * exp(-z^2/2) / (2*pi)
    g.w2[i] = 2.0 * (double)wn * cexp(-0.5 * (double)zn * (double)zn)
              * 0.15915494309189535;
  }
  return g;
}
constexpr GL32 GLC = make_gl();

// g(s) = sum_n w2[n] * sech^2(sqrt(s)*z[n]);  sech^2(a) = 4e/(1+e)^2,
// e = exp(-2a). Cutoff a>12.5 (contribution <1e-10; fp32 tanh saturates
// well before that in the reference anyway).
constexpr float tab_entry(double s) {
  double d2 = 2.0 * csqrt(s);
  double acc = 0.0;
  for (int n = 0; n < 32; ++n) {
    double a = d2 * GLC.z[n];
    if (a < 12.5) {
      double e = cexp(-a);
      double t = 1.0 + e;
      acc += GLC.w2[n] * (4.0 * e / (t * t));
    }
  }
  return (float)acc;
}

// Fat cells: (g0, slope, ck = 23.04*slope, pad). Built in 4 constexpr
// quarters to stay under per-initializer constexpr-step limits.
struct alignas(16) Cell { float g0, sl, ck, pad; };
struct alignas(16) Quarter { Cell c[82]; };
constexpr Quarter make_q(int b) {
  Quarter q{};
  float smp[83]{};
  for (int j = 0; j < 83; ++j)
    smp[j] = tab_entry((double)(b + j) * (1.0 / 16.0));
  for (int j = 0; j < 82; ++j) {
    float sl = smp[j + 1] - smp[j];
    q.c[j] = Cell{smp[j], sl, 23.04f * sl, 0.0f};   // 1.44/h = 23.04
  }
  return q;
}
constexpr Quarter QA = make_q(0), QB = make_q(82), QC = make_q(164),
                  QD = make_q(246);
struct alignas(16) Tab { Cell c[NCELL]; };
constexpr Tab make_tab() {
  Tab t{};
  for (int j = 0; j < 82; ++j) {
    t.c[j]       = QA.c[j];
    t.c[82 + j]  = QB.c[j];
    t.c[164 + j] = QC.c[j];
    t.c[246 + j] = QD.c[j];
  }
  return t;
}
__device__ constexpr Tab TAB = make_tab();

// ---------------- scan pieces -----------------------------------------------
// prep: per-step table lookup + linearization constants (independent of k,v)
__device__ __forceinline__ void prep8(const float* uu, const float4* q,
                                      float* base, float* ck) {
#pragma unroll
  for (int j = 0; j < 8; ++j) {
    float x = fminf(10.24f * uu[j] * uu[j], 327.99f);  // 16 * 0.64 * u^2
    int   i = (int)x;
    float f = FRACTF(x);
    float4 c = q[i];                          // one ds_read_b128
    base[j] = fmaf(f, c.y, c.x);
    ck[j]   = c.z;
  }
}
// run: the serial recurrence; critical chain = mul,fma,fma per step
template <bool EMIT>
__device__ __forceinline__ void run8(const float* uu, const float* base,
                                     const float* ck, float& k, float& v,
                                     float* z) {
#pragma unroll
  for (int j = 0; j < 8; ++j) {
    float th = fmaf(0.18f, k, 0.1f * v);      // parallel to gi path
    float gi = fmaf(ck[j], k * k, base[j]);
    float kn = fmaf(gi, th, 0.8f * k);
    v = fmaf(0.2f, uu[j], 0.8f * v);
    if (EMIT) z[j] = 0.7f * gi * kn;
    k = kn;
  }
}

__global__ __launch_bounds__(THREADS, 1) void scan1_kernel(
    const float* __restrict__ u, float* __restrict__ out) {
  __shared__ float4 q[NCELL];                 // 5.25 KiB

  const int tid = threadIdx.x;
  const int t   = blockIdx.x * THREADS + tid;
  const int g8  = t * CHUNK;
  if (t == 0) out[0] = 0.0f;

  // ---- issue all u loads first --------------------------------------------
  const int base4 = (g8 - W_STEPS) >> 2;
  const float4* __restrict__ up = (const float4*)u;
  float uu[NSTEP];
#pragma unroll
  for (int j = 0; j < NSTEP / 4; ++j) {
    int idx = base4 + j;
    float4 w = up[max(idx, 0)];
    bool ok = (idx >= 0);                     // first block: u=0 pre-history
    uu[4 * j + 0] = ok ? w.x : 0.0f;
    uu[4 * j + 1] = ok ? w.y : 0.0f;
    uu[4 * j + 2] = ok ? w.z : 0.0f;
    uu[4 * j + 3] = ok ? w.w : 0.0f;
  }

  // ---- table: copy .rodata -> LDS -----------------------------------------
  const float4* __restrict__ tsrc = reinterpret_cast<const float4*>(TAB.c);
  for (int i = tid; i < NCELL; i += THREADS) q[i] = tsrc[i];
  __syncthreads();

  // ---- scan: 6 groups of 8 steps, lookups pipelined 2 groups ahead --------
  float k = 0.0f, v = 0.0f, z[8];
  float B0[8], C0[8], B1[8], C1[8];
  prep8(uu + 0,  q, B0, C0);
  prep8(uu + 8,  q, B1, C1);
  run8<false>(uu + 0,  B0, C0, k, v, z);
  prep8(uu + 16, q, B0, C0);
  run8<false>(uu + 8,  B1, C1, k, v, z);
  prep8(uu + 24, q, B1, C1);
  run8<false>(uu + 16, B0, C0, k, v, z);
  prep8(uu + 32, q, B0, C0);
  run8<false>(uu + 24, B1, C1, k, v, z);
  prep8(uu + 40, q, B1, C1);
  run8<false>(uu + 32, B0, C0, k, v, z);
  run8<true>(uu + 40, B1, C1, k, v, z);

#pragma unroll
  for (int j = 0; j < 8; ++j) out[g8 + 1 + j] = z[j];
}

extern "C" void kernel_launch(void* const* d_in, const int* in_sizes, int n_in,
                              void* d_out, int out_size, void* d_ws,
                              size_t ws_size, hipStream_t stream) {
  const float* u = (const float*)d_in[0];
  float* out = (float*)d_out;
  const int T = in_sizes[0];                  // 524288
  const int nblock = T / (CHUNK * THREADS);   // 256
  scan1_kernel<<<nblock, THREADS, 0, stream>>>(u, out);
}